// Round 1
// baseline (117.322 us; speedup 1.0000x reference)
//
#include <hip/hip_runtime.h>

#define HH 768
#define WW 768
#define HP 770
#define WP 770

// One thread per output pixel. All conv/pad semantics collapsed to a clamped
// 3x3 stencil on u + 2x2 weight reads from a,b,c.
//
// Derivation: with v1..v4 the weighted-gradient fields of the reference,
// output (i,j) needs: Au = 0.5*( v1(P11)-v1(P10) + v2(P01)-v2(P00)
//                              + v3(P11)-v3(P01) + v4(P10)-v4(P00) )
// grouped per position:  -(v2+v4)@P00, (v2-v3)@P01, (v4-v1)@P10, (v1+v3)@P11.
// Weights: w1a=a*(1-alpha)/2, w2a=a*alpha/2, w1b=(b-g|b|)/4, w2b=(b+g|b|)/4
// (g=1-2alpha; identical to b*(1-+beta)/4 with beta=g*sign(b)), w1c/w2c like a.
__global__ __launch_bounds__(256) void diffusion_kernel(
    const float* __restrict__ u,
    const float* __restrict__ a,
    const float* __restrict__ b,
    const float* __restrict__ c,
    const float* __restrict__ alpha_p,
    const float* __restrict__ tau_p,
    float* __restrict__ out)
{
    const int j  = blockIdx.x * 64 + (threadIdx.x & 63);   // column
    const int i  = blockIdx.y * 4  + (threadIdx.x >> 6);   // row
    const int bc = blockIdx.z;                             // batch*channel

    const float alpha = *alpha_p;
    const float tau   = *tau_p;
    const float c1 = (1.0f - alpha) * 0.5f;   // w1a/w1c multiplier
    const float c2 = alpha * 0.5f;            // w2a/w2c multiplier
    const float g  = 1.0f - 2.0f * alpha;

    const float* __restrict__ ub = u + (size_t)bc * (HH * WW);
    const float* __restrict__ ab = a + (size_t)bc * (HP * WP);
    const float* __restrict__ bb = b + (size_t)bc * (HP * WP);
    const float* __restrict__ cb = c + (size_t)bc * (HP * WP);

    const int i1 = min(i + 1, HH - 1);
    const int i2 = min(i + 2, HH - 1);
    const int j1 = min(j + 1, WW - 1);
    const int j2 = min(j + 2, WW - 1);

    // clamped 3x3 u neighborhood
    const float u00 = ub[(size_t)i  * WW + j ];
    const float u01 = ub[(size_t)i  * WW + j1];
    const float u02 = ub[(size_t)i  * WW + j2];
    const float u10 = ub[(size_t)i1 * WW + j ];
    const float u11 = ub[(size_t)i1 * WW + j1];
    const float u12 = ub[(size_t)i1 * WW + j2];
    const float u20 = ub[(size_t)i2 * WW + j ];
    const float u21 = ub[(size_t)i2 * WW + j1];
    const float u22 = ub[(size_t)i2 * WW + j2];

    // weight base index: sliced array index (p,q) -> original (p+1, q+1)
    const size_t wbase = (size_t)(i + 1) * WP + (j + 1);

    float acc = 0.0f;

    // ---- P00 = (i, j): s = -(v2+v4) ----
    {
        const float A = ab[wbase], B = bb[wbase], Cv = cb[wbase];
        const float w1a = A * c1, w2a = A * c2;
        const float gb  = g * fabsf(B);
        const float w1b = (B - gb) * 0.25f, w2b = (B + gb) * 0.25f;
        const float w1c = Cv * c1, w2c = Cv * c2;
        const float ux1 = u01 - u00, ux2 = u11 - u10;
        const float uy1 = u10 - u00, uy2 = u11 - u01;
        acc -= (w2a + w2b) * ux1 + (w1a + w1b) * ux2
             + (w2b + w2c) * uy1 + (w1b + w1c) * uy2;
    }
    // ---- P01 = (i, j+1): s = v2 - v3 ----
    {
        const float A = ab[wbase + 1], B = bb[wbase + 1], Cv = cb[wbase + 1];
        const float w1a = A * c1, w2a = A * c2;
        const float gb  = g * fabsf(B);
        const float w1b = (B - gb) * 0.25f, w2b = (B + gb) * 0.25f;
        const float w1c = Cv * c1, w2c = Cv * c2;
        const float ux1 = u02 - u01, ux2 = u12 - u11;
        const float uy1 = u11 - u01, uy2 = u12 - u02;
        acc += (w2a - w1b) * ux1 + (w1a - w2b) * ux2
             + (w2b - w1c) * uy1 + (w1b - w2c) * uy2;
    }
    // ---- P10 = (i+1, j): s = v4 - v1 ----
    {
        const float A = ab[wbase + WP], B = bb[wbase + WP], Cv = cb[wbase + WP];
        const float w1a = A * c1, w2a = A * c2;
        const float gb  = g * fabsf(B);
        const float w1b = (B - gb) * 0.25f, w2b = (B + gb) * 0.25f;
        const float w1c = Cv * c1, w2c = Cv * c2;
        const float ux1 = u11 - u10, ux2 = u21 - u20;
        const float uy1 = u20 - u10, uy2 = u21 - u11;
        acc += (w2b - w1a) * ux1 + (w1b - w2a) * ux2
             + (w2c - w1b) * uy1 + (w1c - w2b) * uy2;
    }
    // ---- P11 = (i+1, j+1): s = v1 + v3 ----
    {
        const float A = ab[wbase + WP + 1], B = bb[wbase + WP + 1], Cv = cb[wbase + WP + 1];
        const float w1a = A * c1, w2a = A * c2;
        const float gb  = g * fabsf(B);
        const float w1b = (B - gb) * 0.25f, w2b = (B + gb) * 0.25f;
        const float w1c = Cv * c1, w2c = Cv * c2;
        const float ux1 = u12 - u11, ux2 = u22 - u21;
        const float uy1 = u21 - u11, uy2 = u22 - u12;
        acc += (w1a + w1b) * ux1 + (w2a + w2b) * ux2
             + (w1b + w1c) * uy1 + (w2b + w2c) * uy2;
    }

    out[(size_t)bc * (HH * WW) + (size_t)i * WW + j] = u00 + tau * 0.5f * acc;
}

extern "C" void kernel_launch(void* const* d_in, const int* in_sizes, int n_in,
                              void* d_out, int out_size, void* d_ws, size_t ws_size,
                              hipStream_t stream) {
    const float* u     = (const float*)d_in[0];
    const float* a     = (const float*)d_in[1];
    const float* b     = (const float*)d_in[2];
    const float* c     = (const float*)d_in[3];
    // d_in[4..7] are the stencil tensors (baked into the kernel algebra)
    const float* alpha = (const float*)d_in[8];
    const float* tau   = (const float*)d_in[9];
    float* out = (float*)d_out;

    dim3 block(256, 1, 1);
    dim3 grid(WW / 64, HH / 4, 32);   // 64 cols x 4 rows per block, 32 = B*C
    diffusion_kernel<<<grid, block, 0, stream>>>(u, a, b, c, alpha, tau, out);
}

// Round 3
// 86.972 us; speedup vs baseline: 1.3490x; 1.3490x over previous
//
#include <hip/hip_runtime.h>

#define HH 768
#define WW 768
#define HP 770
#define WP 770

// 4 output pixels per thread, vectorized loads.
// Collapsed algebra (see R0 derivation):
//   Au(i,j) = 0.5 * [ -(v2+v4)@P00 + (v2-v3)@P01 + (v4-v1)@P10 + (v1+v3)@P11 ]
// Weights at original (770-wide) coords never clamp; u uses clamped 3x6 nbhd.

typedef float f4 __attribute__((ext_vector_type(4)));

__device__ inline f4 ld4u(const float* p) {
    f4 v;
    __builtin_memcpy(&v, p, sizeof(f4));   // 4B-aligned dwordx4 — OK on gfx950
    return v;
}

__global__ __launch_bounds__(256) void diffusion_kernel(
    const float* __restrict__ u,
    const float* __restrict__ a,
    const float* __restrict__ b,
    const float* __restrict__ c,
    const float* __restrict__ alpha_p,
    const float* __restrict__ tau_p,
    float* __restrict__ out)
{
    const int lane = threadIdx.x & 63;
    const int rsub = threadIdx.x >> 6;
    const int j0 = (blockIdx.x * 64 + lane) * 4;   // first of 4 columns
    const int i  = blockIdx.y * 4 + rsub;          // row
    const int bc = blockIdx.z;

    const float alpha = *alpha_p;
    const float tau   = *tau_p;
    const float c1 = (1.0f - alpha) * 0.5f;
    const float c2 = alpha * 0.5f;
    const float g  = 1.0f - 2.0f * alpha;

    const float* __restrict__ ub = u + (size_t)bc * (HH * WW);
    const float* __restrict__ ab = a + (size_t)bc * (HP * WP);
    const float* __restrict__ bb = b + (size_t)bc * (HP * WP);
    const float* __restrict__ cb = c + (size_t)bc * (HP * WP);

    const int r1 = min(i + 1, HH - 1);
    const int r2 = min(i + 2, HH - 1);

    // ---- u: 3 rows x 6 columns (clamped at right edge) ----
    const float* p0 = ub + (size_t)i  * WW + j0;
    const float* p1 = ub + (size_t)r1 * WW + j0;
    const float* p2 = ub + (size_t)r2 * WW + j0;

    float u0[6], u1[6], u2[6];
    {
        f4 t;
        t = *(const f4*)p0; u0[0]=t.x; u0[1]=t.y; u0[2]=t.z; u0[3]=t.w;
        t = *(const f4*)p1; u1[0]=t.x; u1[1]=t.y; u1[2]=t.z; u1[3]=t.w;
        t = *(const f4*)p2; u2[0]=t.x; u2[1]=t.y; u2[2]=t.z; u2[3]=t.w;
        if (j0 + 7 < WW) {
            t = *(const f4*)(p0 + 4); u0[4]=t.x; u0[5]=t.y;
            t = *(const f4*)(p1 + 4); u1[4]=t.x; u1[5]=t.y;
            t = *(const f4*)(p2 + 4); u2[4]=t.x; u2[5]=t.y;
        } else {   // j0 == 764: cols 768,769 clamp to 767 (= element 3)
            u0[4]=u0[3]; u0[5]=u0[3];
            u1[4]=u1[3]; u1[5]=u1[3];
            u2[4]=u2[3]; u2[5]=u2[3];
        }
    }

    // ---- weights: rows i+1, i+2 (original idx), cols j0+1 .. j0+5 ----
    const float* wa1 = ab + (size_t)(i + 1) * WP + (j0 + 1);
    const float* wa2 = ab + (size_t)(i + 2) * WP + (j0 + 1);
    const float* wb1 = bb + (size_t)(i + 1) * WP + (j0 + 1);
    const float* wb2 = bb + (size_t)(i + 2) * WP + (j0 + 1);
    const float* wc1 = cb + (size_t)(i + 1) * WP + (j0 + 1);
    const float* wc2 = cb + (size_t)(i + 2) * WP + (j0 + 1);

    float A1[5], A2[5], B1[5], B2[5], C1[5], C2[5];
    {
        f4 t;
        t = ld4u(wa1); A1[0]=t.x; A1[1]=t.y; A1[2]=t.z; A1[3]=t.w; A1[4]=wa1[4];
        t = ld4u(wa2); A2[0]=t.x; A2[1]=t.y; A2[2]=t.z; A2[3]=t.w; A2[4]=wa2[4];
        t = ld4u(wb1); B1[0]=t.x; B1[1]=t.y; B1[2]=t.z; B1[3]=t.w; B1[4]=wb1[4];
        t = ld4u(wb2); B2[0]=t.x; B2[1]=t.y; B2[2]=t.z; B2[3]=t.w; B2[4]=wb2[4];
        t = ld4u(wc1); C1[0]=t.x; C1[1]=t.y; C1[2]=t.z; C1[3]=t.w; C1[4]=wc1[4];
        t = ld4u(wc2); C2[0]=t.x; C2[1]=t.y; C2[2]=t.z; C2[3]=t.w; C2[4]=wc2[4];
    }

    auto wts = [&](float A, float B, float Cv,
                   float& w1a, float& w2a, float& w1b, float& w2b,
                   float& w1c, float& w2c) {
        w1a = A * c1; w2a = A * c2;
        const float gb = g * fabsf(B);
        w1b = (B - gb) * 0.25f; w2b = (B + gb) * 0.25f;
        w1c = Cv * c1; w2c = Cv * c2;
    };

    float res[4];
#pragma unroll
    for (int p = 0; p < 4; ++p) {
        float acc = 0.0f;
        float w1a, w2a, w1b, w2b, w1c, w2c;
        float ux1, ux2, uy1, uy2;

        // P00 (row1, col p): s = -(v2+v4)
        wts(A1[p], B1[p], C1[p], w1a, w2a, w1b, w2b, w1c, w2c);
        ux1 = u0[p+1] - u0[p];   ux2 = u1[p+1] - u1[p];
        uy1 = u1[p]   - u0[p];   uy2 = u1[p+1] - u0[p+1];
        acc -= (w2a + w2b) * ux1 + (w1a + w1b) * ux2
             + (w2b + w2c) * uy1 + (w1b + w1c) * uy2;

        // P01 (row1, col p+1): s = v2 - v3
        wts(A1[p+1], B1[p+1], C1[p+1], w1a, w2a, w1b, w2b, w1c, w2c);
        ux1 = u0[p+2] - u0[p+1]; ux2 = u1[p+2] - u1[p+1];
        uy1 = u1[p+1] - u0[p+1]; uy2 = u1[p+2] - u0[p+2];
        acc += (w2a - w1b) * ux1 + (w1a - w2b) * ux2
             + (w2b - w1c) * uy1 + (w1b - w2c) * uy2;

        // P10 (row2, col p): s = v4 - v1
        wts(A2[p], B2[p], C2[p], w1a, w2a, w1b, w2b, w1c, w2c);
        ux1 = u1[p+1] - u1[p];   ux2 = u2[p+1] - u2[p];
        uy1 = u2[p]   - u1[p];   uy2 = u2[p+1] - u1[p+1];
        acc += (w2b - w1a) * ux1 + (w1b - w2a) * ux2
             + (w2c - w1b) * uy1 + (w1c - w2b) * uy2;

        // P11 (row2, col p+1): s = v1 + v3
        wts(A2[p+1], B2[p+1], C2[p+1], w1a, w2a, w1b, w2b, w1c, w2c);
        ux1 = u1[p+2] - u1[p+1]; ux2 = u2[p+2] - u2[p+1];
        uy1 = u2[p+1] - u1[p+1]; uy2 = u2[p+2] - u1[p+2];
        acc += (w1a + w1b) * ux1 + (w2a + w2b) * ux2
             + (w1b + w1c) * uy1 + (w2b + w2c) * uy2;

        res[p] = u0[p] + tau * 0.5f * acc;
    }

    f4 o;
    o.x = res[0]; o.y = res[1]; o.z = res[2]; o.w = res[3];
    __builtin_nontemporal_store(o, (f4*)(out + (size_t)bc * (HH * WW) + (size_t)i * WW + j0));
}

extern "C" void kernel_launch(void* const* d_in, const int* in_sizes, int n_in,
                              void* d_out, int out_size, void* d_ws, size_t ws_size,
                              hipStream_t stream) {
    const float* u     = (const float*)d_in[0];
    const float* a     = (const float*)d_in[1];
    const float* b     = (const float*)d_in[2];
    const float* c     = (const float*)d_in[3];
    const float* alpha = (const float*)d_in[8];
    const float* tau   = (const float*)d_in[9];
    float* out = (float*)d_out;

    dim3 block(256, 1, 1);
    dim3 grid(WW / 256, HH / 4, 32);   // 3 x 192 x 32; 256 cols x 4 rows per block
    diffusion_kernel<<<grid, block, 0, stream>>>(u, a, b, c, alpha, tau, out);
}

// Round 4
// 82.529 us; speedup vs baseline: 1.4216x; 1.0538x over previous
//
#include <hip/hip_runtime.h>

#define HH 768
#define WW 768
#define HP 770
#define WP 770

// 2 output rows x 4 cols per thread. Collapsed algebra (see R0):
//   Au(i,j) = 0.5 * [ -(v2+v4)@P00 + (v2-v3)@P01 + (v4-v1)@P10 + (v1+v3)@P11 ]
// P00=(i+1,j+1) etc. in original 770-wide weight coords (never clamps:
// i<=766 -> rows i+1..i+3 <= 769; j0<=764 -> cols j0+1..j0+5 <= 769).
// u uses a clamped 4x6 neighborhood shared across the two output rows.

typedef float f4 __attribute__((ext_vector_type(4)));

__device__ inline f4 ld4u(const float* p) {
    f4 v;
    __builtin_memcpy(&v, p, sizeof(f4));   // 4B-aligned dwordx4
    return v;
}

__global__ __launch_bounds__(256) void diffusion_kernel(
    const float* __restrict__ u,
    const float* __restrict__ a,
    const float* __restrict__ b,
    const float* __restrict__ c,
    const float* __restrict__ alpha_p,
    const float* __restrict__ tau_p,
    float* __restrict__ out)
{
    const int lane = threadIdx.x & 63;
    const int rsub = threadIdx.x >> 6;
    const int j0 = (blockIdx.x * 64 + lane) * 4;    // first of 4 columns
    const int i0 = blockIdx.y * 8 + rsub * 2;       // first of 2 output rows
    const int bc = blockIdx.z;

    const float alpha = *alpha_p;
    const float tau   = *tau_p;
    const float c1 = (1.0f - alpha) * 0.5f;
    const float c2 = alpha * 0.5f;
    const float g  = 1.0f - 2.0f * alpha;

    const float* __restrict__ ub = u + (size_t)bc * (HH * WW);
    const float* __restrict__ ab = a + (size_t)bc * (HP * WP);
    const float* __restrict__ bb = b + (size_t)bc * (HP * WP);
    const float* __restrict__ cb = c + (size_t)bc * (HP * WP);

    // u rows i0..i0+3, clamped at 767 (i0 <= 766, i0+1 <= 767 always valid)
    int ur[4];
    ur[0] = i0; ur[1] = i0 + 1;
    ur[2] = min(i0 + 2, HH - 1); ur[3] = min(i0 + 3, HH - 1);

    // ---- u: 4 rows x 6 cols (clamped at right edge) ----
    float U[4][6];
    const bool interior = (j0 + 7 < WW);
#pragma unroll
    for (int rr = 0; rr < 4; ++rr) {
        const float* pr = ub + (size_t)ur[rr] * WW + j0;
        f4 t = *(const f4*)pr;
        U[rr][0] = t.x; U[rr][1] = t.y; U[rr][2] = t.z; U[rr][3] = t.w;
        if (interior) {
            f4 s = *(const f4*)(pr + 4);
            U[rr][4] = s.x; U[rr][5] = s.y;
        } else {            // j0 == 764: cols 768,769 clamp to 767 (elem 3)
            U[rr][4] = t.w; U[rr][5] = t.w;
        }
    }

    // ---- weights: rows i0+1..i0+3 (original idx), cols j0+1..j0+5 ----
    float A[3][5], B[3][5], C[3][5];
#pragma unroll
    for (int k = 0; k < 3; ++k) {
        const size_t roff = (size_t)(i0 + 1 + k) * WP + (j0 + 1);
        f4 t;
        t = ld4u(ab + roff); A[k][0]=t.x; A[k][1]=t.y; A[k][2]=t.z; A[k][3]=t.w; A[k][4]=ab[roff+4];
        t = ld4u(bb + roff); B[k][0]=t.x; B[k][1]=t.y; B[k][2]=t.z; B[k][3]=t.w; B[k][4]=bb[roff+4];
        t = ld4u(cb + roff); C[k][0]=t.x; C[k][1]=t.y; C[k][2]=t.z; C[k][3]=t.w; C[k][4]=cb[roff+4];
    }

    auto wts = [&](float Av, float Bv, float Cv,
                   float& w1a, float& w2a, float& w1b, float& w2b,
                   float& w1c, float& w2c) {
        w1a = Av * c1; w2a = Av * c2;
        const float gb = g * fabsf(Bv);
        w1b = (Bv - gb) * 0.25f; w2b = (Bv + gb) * 0.25f;
        w1c = Cv * c1; w2c = Cv * c2;
    };

#pragma unroll
    for (int r = 0; r < 2; ++r) {
        float res[4];
#pragma unroll
        for (int p = 0; p < 4; ++p) {
            float acc = 0.0f;
            float w1a, w2a, w1b, w2b, w1c, w2c;
            float ux1, ux2, uy1, uy2;

            // P00 (wrow r, col p): s = -(v2+v4)
            wts(A[r][p], B[r][p], C[r][p], w1a, w2a, w1b, w2b, w1c, w2c);
            ux1 = U[r][p+1]   - U[r][p];     ux2 = U[r+1][p+1] - U[r+1][p];
            uy1 = U[r+1][p]   - U[r][p];     uy2 = U[r+1][p+1] - U[r][p+1];
            acc -= (w2a + w2b) * ux1 + (w1a + w1b) * ux2
                 + (w2b + w2c) * uy1 + (w1b + w1c) * uy2;

            // P01 (wrow r, col p+1): s = v2 - v3
            wts(A[r][p+1], B[r][p+1], C[r][p+1], w1a, w2a, w1b, w2b, w1c, w2c);
            ux1 = U[r][p+2]   - U[r][p+1];   ux2 = U[r+1][p+2] - U[r+1][p+1];
            uy1 = U[r+1][p+1] - U[r][p+1];   uy2 = U[r+1][p+2] - U[r][p+2];
            acc += (w2a - w1b) * ux1 + (w1a - w2b) * ux2
                 + (w2b - w1c) * uy1 + (w1b - w2c) * uy2;

            // P10 (wrow r+1, col p): s = v4 - v1
            wts(A[r+1][p], B[r+1][p], C[r+1][p], w1a, w2a, w1b, w2b, w1c, w2c);
            ux1 = U[r+1][p+1] - U[r+1][p];   ux2 = U[r+2][p+1] - U[r+2][p];
            uy1 = U[r+2][p]   - U[r+1][p];   uy2 = U[r+2][p+1] - U[r+1][p+1];
            acc += (w2b - w1a) * ux1 + (w1b - w2a) * ux2
                 + (w2c - w1b) * uy1 + (w1c - w2b) * uy2;

            // P11 (wrow r+1, col p+1): s = v1 + v3
            wts(A[r+1][p+1], B[r+1][p+1], C[r+1][p+1], w1a, w2a, w1b, w2b, w1c, w2c);
            ux1 = U[r+1][p+2] - U[r+1][p+1]; ux2 = U[r+2][p+2] - U[r+2][p+1];
            uy1 = U[r+2][p+1] - U[r+1][p+1]; uy2 = U[r+2][p+2] - U[r+1][p+2];
            acc += (w1a + w1b) * ux1 + (w2a + w2b) * ux2
                 + (w1b + w1c) * uy1 + (w2b + w2c) * uy2;

            res[p] = U[r][p] + tau * 0.5f * acc;
        }

        f4 o;
        o.x = res[0]; o.y = res[1]; o.z = res[2]; o.w = res[3];
        __builtin_nontemporal_store(
            o, (f4*)(out + (size_t)bc * (HH * WW) + (size_t)(i0 + r) * WW + j0));
    }
}

extern "C" void kernel_launch(void* const* d_in, const int* in_sizes, int n_in,
                              void* d_out, int out_size, void* d_ws, size_t ws_size,
                              hipStream_t stream) {
    const float* u     = (const float*)d_in[0];
    const float* a     = (const float*)d_in[1];
    const float* b     = (const float*)d_in[2];
    const float* c     = (const float*)d_in[3];
    const float* alpha = (const float*)d_in[8];
    const float* tau   = (const float*)d_in[9];
    float* out = (float*)d_out;

    dim3 block(256, 1, 1);
    dim3 grid(WW / 256, HH / 8, 32);   // 3 x 96 x 32; 256 cols x 8 rows per block
    diffusion_kernel<<<grid, block, 0, stream>>>(u, a, b, c, alpha, tau, out);
}

// Round 5
// 68.282 us; speedup vs baseline: 1.7182x; 1.2086x over previous
//
#include <hip/hip_runtime.h>

#define HH 768
#define WW 768
#define HP 770
#define WP 770
#define ROWS 8
#define TILES 192   // 4 output cols per thread; 192*4 = 768
#define BANDS 96    // 96*8 = 768

// Register-carried row-walking stencil with 1-row software prefetch.
// Collapsed algebra (R0 derivation):
//   Au(i,j) = 0.5 * [ -(v2+v4)@P00 + (v2-v3)@P01 + (v4-v1)@P10 + (v1+v3)@P11 ]
// P00=(i+1,j+1) in original 770-wide weight coords (rows i+1..i+2 <= 769,
// cols j0+1..j0+5 <= 769: never clamps). u uses clamped rows / right edge.

typedef float f4 __attribute__((ext_vector_type(4)));

__device__ inline f4 ld4u(const float* p) {
    f4 v;
    __builtin_memcpy(&v, p, sizeof(f4));   // 4B-aligned dwordx4
    return v;
}

__global__ __launch_bounds__(256) void diffusion_kernel(
    const float* __restrict__ u,
    const float* __restrict__ a,
    const float* __restrict__ b,
    const float* __restrict__ c,
    const float* __restrict__ alpha_p,
    const float* __restrict__ tau_p,
    float* __restrict__ out)
{
    // XCD-bijective swizzle: 2304 blocks, 8 XCDs -> chunks of 288.
    const int bid  = (blockIdx.x & 7) * (TILES * BANDS * 32 / 256 / 8) + (blockIdx.x >> 3);
    const int gtid = bid * 256 + threadIdx.x;
    const int tile = gtid % TILES;
    const int band = (gtid / TILES) % BANDS;
    const int bc   = gtid / (TILES * BANDS);
    const int j0 = tile * 4;
    const int i0 = band * ROWS;
    const bool interior = (j0 + 4) < WW;     // false only for tile 191 (j0=764)

    const float alpha = *alpha_p;
    const float tau   = *tau_p;
    const float c1 = (1.0f - alpha) * 0.5f;
    const float c2 = alpha * 0.5f;
    const float g  = 1.0f - 2.0f * alpha;

    const float* __restrict__ ub = u + (size_t)bc * (HH * WW);
    const float* __restrict__ ab = a + (size_t)bc * (HP * WP);
    const float* __restrict__ bb = b + (size_t)bc * (HP * WP);
    const float* __restrict__ cb = c + (size_t)bc * (HP * WP);
    float* __restrict__ outb = out + (size_t)bc * (HH * WW);

    // carried registers: u rows i, i+1, i+2 (6 cols); weight rows i+1, i+2 (5 cols)
    float u0[6], u1[6], u2[6];
    float a1[5], a2[5], b1[5], b2[5], cc1[5], cc2[5];

    auto load_u = [&](int row, float* dst) {
        const float* pr = ub + (size_t)row * WW + j0;
        f4 t0 = *(const f4*)pr;
        const float* p2 = pr + (interior ? 4 : 0);
        f4 t1 = *(const f4*)p2;
        dst[0] = t0.x; dst[1] = t0.y; dst[2] = t0.z; dst[3] = t0.w;
        dst[4] = interior ? t1.x : t0.w;
        dst[5] = interior ? t1.y : t0.w;
    };
    auto load_w = [&](const float* base, int row, float* dst) {
        const float* pr = base + (size_t)row * WP + (j0 + 1);
        f4 t = ld4u(pr);
        dst[0] = t.x; dst[1] = t.y; dst[2] = t.z; dst[3] = t.w;
        dst[4] = pr[4];
    };

    // prologue: rows for first output row i0
    load_u(i0,     u0);
    load_u(i0 + 1, u1);
    load_u(i0 + 2, u2);      // i0+2 <= 762, no clamp needed here
    load_w(ab, i0 + 1, a1);  load_w(ab, i0 + 2, a2);
    load_w(bb, i0 + 1, b1);  load_w(bb, i0 + 2, b2);
    load_w(cb, i0 + 1, cc1); load_w(cb, i0 + 2, cc2);

    auto wts = [&](float Av, float Bv, float Cv,
                   float& w1a, float& w2a, float& w1b, float& w2b,
                   float& w1c, float& w2c) {
        w1a = Av * c1; w2a = Av * c2;
        const float gb = g * fabsf(Bv);
        w1b = (Bv - gb) * 0.25f; w2b = (Bv + gb) * 0.25f;
        w1c = Cv * c1; w2c = Cv * c2;
    };

#pragma unroll
    for (int r = 0; r < ROWS; ++r) {
        const int ri = i0 + r;

        // ---- prefetch row ri+3 (u clamped; weights never clamp, max 769) ----
        float pu[6], pa[5], pb[5], pc[5];
        if (r < ROWS - 1) {
            load_u(min(ri + 3, HH - 1), pu);
            load_w(ab, ri + 3, pa);
            load_w(bb, ri + 3, pb);
            load_w(cb, ri + 3, pc);
        }

        // ---- compute output row ri ----
        float res[4];
#pragma unroll
        for (int p = 0; p < 4; ++p) {
            float acc = 0.0f;
            float w1a, w2a, w1b, w2b, w1c, w2c;
            float ux1, ux2, uy1, uy2;

            // P00: s = -(v2+v4)
            wts(a1[p], b1[p], cc1[p], w1a, w2a, w1b, w2b, w1c, w2c);
            ux1 = u0[p+1] - u0[p];   ux2 = u1[p+1] - u1[p];
            uy1 = u1[p]   - u0[p];   uy2 = u1[p+1] - u0[p+1];
            acc -= (w2a + w2b) * ux1 + (w1a + w1b) * ux2
                 + (w2b + w2c) * uy1 + (w1b + w1c) * uy2;

            // P01: s = v2 - v3
            wts(a1[p+1], b1[p+1], cc1[p+1], w1a, w2a, w1b, w2b, w1c, w2c);
            ux1 = u0[p+2] - u0[p+1]; ux2 = u1[p+2] - u1[p+1];
            uy1 = u1[p+1] - u0[p+1]; uy2 = u1[p+2] - u0[p+2];
            acc += (w2a - w1b) * ux1 + (w1a - w2b) * ux2
                 + (w2b - w1c) * uy1 + (w1b - w2c) * uy2;

            // P10: s = v4 - v1
            wts(a2[p], b2[p], cc2[p], w1a, w2a, w1b, w2b, w1c, w2c);
            ux1 = u1[p+1] - u1[p];   ux2 = u2[p+1] - u2[p];
            uy1 = u2[p]   - u1[p];   uy2 = u2[p+1] - u1[p+1];
            acc += (w2b - w1a) * ux1 + (w1b - w2a) * ux2
                 + (w2c - w1b) * uy1 + (w1c - w2b) * uy2;

            // P11: s = v1 + v3
            wts(a2[p+1], b2[p+1], cc2[p+1], w1a, w2a, w1b, w2b, w1c, w2c);
            ux1 = u1[p+2] - u1[p+1]; ux2 = u2[p+2] - u2[p+1];
            uy1 = u2[p+1] - u1[p+1]; uy2 = u2[p+2] - u1[p+2];
            acc += (w1a + w1b) * ux1 + (w2a + w2b) * ux2
                 + (w1b + w1c) * uy1 + (w2b + w2c) * uy2;

            res[p] = u0[p] + tau * 0.5f * acc;
        }

        f4 o;
        o.x = res[0]; o.y = res[1]; o.z = res[2]; o.w = res[3];
        __builtin_nontemporal_store(o, (f4*)(outb + (size_t)ri * WW + j0));

        // ---- rotate carried registers ----
        if (r < ROWS - 1) {
#pragma unroll
            for (int q = 0; q < 6; ++q) { u0[q] = u1[q]; u1[q] = u2[q]; u2[q] = pu[q]; }
#pragma unroll
            for (int q = 0; q < 5; ++q) {
                a1[q] = a2[q];  a2[q] = pa[q];
                b1[q] = b2[q];  b2[q] = pb[q];
                cc1[q] = cc2[q]; cc2[q] = pc[q];
            }
        }
    }
}

extern "C" void kernel_launch(void* const* d_in, const int* in_sizes, int n_in,
                              void* d_out, int out_size, void* d_ws, size_t ws_size,
                              hipStream_t stream) {
    const float* u     = (const float*)d_in[0];
    const float* a     = (const float*)d_in[1];
    const float* b     = (const float*)d_in[2];
    const float* c     = (const float*)d_in[3];
    const float* alpha = (const float*)d_in[8];
    const float* tau   = (const float*)d_in[9];
    float* out = (float*)d_out;

    // 192 tiles * 96 bands * 32 bc = 589824 threads = 2304 blocks
    dim3 block(256, 1, 1);
    dim3 grid(TILES * BANDS * 32 / 256, 1, 1);
    diffusion_kernel<<<grid, block, 0, stream>>>(u, a, b, c, alpha, tau, out);
}